// Round 1
// baseline (649.086 us; speedup 1.0000x reference)
//
#include <hip/hip_runtime.h>

#define BATCH 8
#define SEQL 16384
#define NCH 128
#define NH 4
#define HD 32
#define GEPS 1e-5f
#define TILE 64
#define XS_PITCH 132     // 128 + 4 pad, multiple of 4 for b128 alignment
#define EKV_PITCH 260    // 256 + 4 pad

// workspace float offsets
#define WKV_OFF 0            // [128][256]  W_{k,v} transposed: [c][o'], o' = o-128
#define WQ_OFF 32768         // [128][128]  W_q transposed
#define WOUT_OFF 49152       // [128][128]  W_out transposed
#define CTX_OFF 65536        // [8][4][32][32] context accumulator
#define Z_OFF 98304          // [8][128]  k-softmax denominators
#define GNS_OFF 99328        // [8][2]  (sum, sumsq)
#define GNF_OFF 99344        // [8][2]  (mean, rstd)
#define ZERO_OFF CTX_OFF
#define ZERO_CNT (GNF_OFF - CTX_OFF)

__global__ void k_prep(const float* __restrict__ wqkv, const float* __restrict__ wout,
                       float* __restrict__ ws) {
    int i = blockIdx.x * 256 + threadIdx.x;
    if (i < 384 * 128) {
        int o = i >> 7, c = i & 127;
        float v = wqkv[i];
        if (o < 128) ws[WQ_OFF + c * 128 + o] = v;
        else         ws[WKV_OFF + c * 256 + (o - 128)] = v;
    }
    if (i < 128 * 128) {
        int o = i >> 7, c = i & 127;
        ws[WOUT_OFF + c * 128 + o] = wout[i];
    }
}

// Pass 1: k,v = W_kv @ x per token; ek = exp(k); ctx_raw += ek (outer) v; Z += ek
__global__ __launch_bounds__(256) void k_pass1(const float* __restrict__ x,
                                               float* __restrict__ ws) {
    __shared__ float sbuf[TILE * EKV_PITCH];
    const int t = threadIdx.x;
    const int cg = t & 63, tg = t >> 6;          // GEMM map: 4 ch x 16 tok per thread
    const int hc = t & 127, dh = t >> 7;         // context map: (head-chan, d-half)
    const int h = hc >> 5, cc = hc & 31;
    const int g = blockIdx.x;
    const int batch = g >> 6, sub = g & 63;      // 64 blocks per batch, 4 chunks each
    const float* __restrict__ wkv = ws + WKV_OFF;
    const bool isk = (cg < 32);

    float cacc[16];
#pragma unroll
    for (int i = 0; i < 16; i++) cacc[i] = 0.f;
    float z4[4] = {0.f, 0.f, 0.f, 0.f};

    for (int rep = 0; rep < 4; rep++) {
        const int chunk = sub + rep * 64;
        const float* xb = x + (size_t)(batch * SEQL + chunk * TILE) * NCH;
        __syncthreads();   // previous iteration's sbuf reads done
        // stage x tile token-major [64][XS_PITCH]
#pragma unroll
        for (int r = 0; r < 8; r++) {
            int e = t + r * 256;
            int j = e >> 5, cq = e & 31;
            float4 v = ((const float4*)xb)[e];
            *(float4*)&sbuf[j * XS_PITCH + cq * 4] = v;
        }
        __syncthreads();
        // GEMM: 256 out channels (k then v) x 64 tokens
        float acc[4][16];
#pragma unroll
        for (int i = 0; i < 4; i++)
#pragma unroll
            for (int j = 0; j < 16; j++) acc[i][j] = 0.f;
        for (int c = 0; c < NCH; c += 4) {
            float4 w0 = *(const float4*)&wkv[(c + 0) * 256 + cg * 4];
            float4 w1 = *(const float4*)&wkv[(c + 1) * 256 + cg * 4];
            float4 w2 = *(const float4*)&wkv[(c + 2) * 256 + cg * 4];
            float4 w3 = *(const float4*)&wkv[(c + 3) * 256 + cg * 4];
#pragma unroll
            for (int j = 0; j < 16; j++) {
                float4 xv = *(const float4*)&sbuf[(tg * 16 + j) * XS_PITCH + c];
                acc[0][j] += w0.x * xv.x + w1.x * xv.y + w2.x * xv.z + w3.x * xv.w;
                acc[1][j] += w0.y * xv.x + w1.y * xv.y + w2.y * xv.z + w3.y * xv.w;
                acc[2][j] += w0.z * xv.x + w1.z * xv.y + w2.z * xv.z + w3.z * xv.w;
                acc[3][j] += w0.w * xv.x + w1.w * xv.y + w2.w * xv.z + w3.w * xv.w;
            }
        }
        __syncthreads();   // x-tile reads done; reuse sbuf for ek|v, [64][EKV_PITCH]
#pragma unroll
        for (int j = 0; j < 16; j++) {
            float a0 = acc[0][j], a1 = acc[1][j], a2 = acc[2][j], a3 = acc[3][j];
            if (isk) {
                a0 = __expf(a0); a1 = __expf(a1); a2 = __expf(a2); a3 = __expf(a3);
                z4[0] += a0; z4[1] += a1; z4[2] += a2; z4[3] += a3;
            }
            *(float4*)&sbuf[(tg * 16 + j) * EKV_PITCH + cg * 4] = make_float4(a0, a1, a2, a3);
        }
        __syncthreads();
        // context accumulate: cacc[dd] += ek[j][hc] * v[j][h*32 + dh*16 + dd]
#pragma unroll 4
        for (int j = 0; j < TILE; j++) {
            float e = sbuf[j * EKV_PITCH + hc];
            const float* vr = &sbuf[j * EKV_PITCH + 128 + h * 32 + dh * 16];
            float4 v0 = *(const float4*)&vr[0];
            float4 v1 = *(const float4*)&vr[4];
            float4 v2 = *(const float4*)&vr[8];
            float4 v3 = *(const float4*)&vr[12];
            cacc[0]  += e * v0.x; cacc[1]  += e * v0.y; cacc[2]  += e * v0.z; cacc[3]  += e * v0.w;
            cacc[4]  += e * v1.x; cacc[5]  += e * v1.y; cacc[6]  += e * v1.z; cacc[7]  += e * v1.w;
            cacc[8]  += e * v2.x; cacc[9]  += e * v2.y; cacc[10] += e * v2.z; cacc[11] += e * v2.w;
            cacc[12] += e * v3.x; cacc[13] += e * v3.y; cacc[14] += e * v3.z; cacc[15] += e * v3.w;
        }
    }
    float* ctxg = ws + CTX_OFF + (((batch * NH + h) * HD + cc) * HD + dh * 16);
#pragma unroll
    for (int i = 0; i < 16; i++) atomicAdd(&ctxg[i], cacc[i]);
    if (isk) {
        float* Zg = ws + Z_OFF + batch * NCH + cg * 4;
#pragma unroll
        for (int i = 0; i < 4; i++) atomicAdd(&Zg[i], z4[i]);
    }
}

__global__ void k_ctxnorm(float* __restrict__ ws) {
    int i = blockIdx.x * 256 + threadIdx.x;
    if (i < BATCH * NCH * HD) {
        int c = (i >> 5) & 31;
        int bh = i >> 10;
        int b = bh >> 2, hh = bh & 3;
        ws[CTX_OFF + i] /= ws[Z_OFF + b * NCH + hh * 32 + c];
    }
}

// Pass 2: q = W_q @ x; softmax over head-dim * scale; attn = ctx @ q; W_out + bias;
// GN partial sums; write pre-GN result to out in [B,L,C] layout.
__global__ __launch_bounds__(256) void k_pass2(const float* __restrict__ x,
                                               const float* __restrict__ bout,
                                               float* __restrict__ ws,
                                               float* __restrict__ out) {
    __shared__ float xq[TILE * XS_PITCH];
    __shared__ float att[TILE * XS_PITCH];
    const int t = threadIdx.x;
    const int cg = t & 63, tg = t >> 6;          // 2 ch x 16 tok per thread
    const int g = blockIdx.x;
    const int batch = g >> 8, chunk = g & 255;
    const size_t tok0 = (size_t)batch * SEQL + chunk * TILE;
    const float* xb = x + tok0 * NCH;
#pragma unroll
    for (int r = 0; r < 8; r++) {
        int e = t + r * 256;
        int j = e >> 5, cq = e & 31;
        float4 v = ((const float4*)xb)[e];
        *(float4*)&xq[j * XS_PITCH + cq * 4] = v;
    }
    __syncthreads();
    // q GEMM: 128 channels
    float qa[2][16];
#pragma unroll
    for (int i = 0; i < 2; i++)
#pragma unroll
        for (int j = 0; j < 16; j++) qa[i][j] = 0.f;
    const float* wq = ws + WQ_OFF;
    for (int c = 0; c < NCH; c += 4) {
        float2 w0 = *(const float2*)&wq[(c + 0) * 128 + cg * 2];
        float2 w1 = *(const float2*)&wq[(c + 1) * 128 + cg * 2];
        float2 w2 = *(const float2*)&wq[(c + 2) * 128 + cg * 2];
        float2 w3 = *(const float2*)&wq[(c + 3) * 128 + cg * 2];
#pragma unroll
        for (int j = 0; j < 16; j++) {
            float4 xv = *(const float4*)&xq[(tg * 16 + j) * XS_PITCH + c];
            qa[0][j] += w0.x * xv.x + w1.x * xv.y + w2.x * xv.z + w3.x * xv.w;
            qa[1][j] += w0.y * xv.x + w1.y * xv.y + w2.y * xv.z + w3.y * xv.w;
        }
    }
    __syncthreads();   // x reads done; overwrite xq with q
#pragma unroll
    for (int j = 0; j < 16; j++)
        *(float2*)&xq[(tg * 16 + j) * XS_PITCH + cg * 2] = make_float2(qa[0][j], qa[1][j]);
    __syncthreads();
    // per-(token, head) softmax over 32 dims, * scale
    {
        int j = t >> 2, hh = t & 3;
        float* qr = &xq[j * XS_PITCH + hh * 32];
        float ee[32];
        float s = 0.f;
#pragma unroll
        for (int d = 0; d < 32; d++) { ee[d] = __expf(qr[d]); s += ee[d]; }
        float inv = 0.17677669529663687f / s;   // (1/sqrt(32)) / s
#pragma unroll
        for (int d = 0; d < 32; d++) qr[d] = ee[d] * inv;
    }
    __syncthreads();
    // attn: out_attn[ch] = sum_d ctx[b,h,c,d] * p[h,d]
    float aacc[2][16];
#pragma unroll
    for (int i = 0; i < 2; i++)
#pragma unroll
        for (int j = 0; j < 16; j++) aacc[i][j] = 0.f;
    const int ch0 = cg * 2;
    const int h2 = ch0 >> 5, c2 = ch0 & 31;
    const float* cr = ws + CTX_OFF + (size_t)((batch * NH + h2) * HD + c2) * HD;
    for (int d = 0; d < HD; d += 4) {
        float4 ca = *(const float4*)&cr[d];
        float4 cb = *(const float4*)&cr[HD + d];
#pragma unroll
        for (int j = 0; j < 16; j++) {
            float4 p = *(const float4*)&xq[(tg * 16 + j) * XS_PITCH + h2 * 32 + d];
            aacc[0][j] += ca.x * p.x + ca.y * p.y + ca.z * p.z + ca.w * p.w;
            aacc[1][j] += cb.x * p.x + cb.y * p.y + cb.z * p.z + cb.w * p.w;
        }
    }
#pragma unroll
    for (int j = 0; j < 16; j++)
        *(float2*)&att[(tg * 16 + j) * XS_PITCH + ch0] = make_float2(aacc[0][j], aacc[1][j]);
    __syncthreads();
    // W_out GEMM
    float oa[2][16];
#pragma unroll
    for (int i = 0; i < 2; i++)
#pragma unroll
        for (int j = 0; j < 16; j++) oa[i][j] = 0.f;
    const float* wo = ws + WOUT_OFF;
    for (int c = 0; c < NCH; c += 4) {
        float2 w0 = *(const float2*)&wo[(c + 0) * 128 + cg * 2];
        float2 w1 = *(const float2*)&wo[(c + 1) * 128 + cg * 2];
        float2 w2 = *(const float2*)&wo[(c + 2) * 128 + cg * 2];
        float2 w3 = *(const float2*)&wo[(c + 3) * 128 + cg * 2];
#pragma unroll
        for (int j = 0; j < 16; j++) {
            float4 av = *(const float4*)&att[(tg * 16 + j) * XS_PITCH + c];
            oa[0][j] += w0.x * av.x + w1.x * av.y + w2.x * av.z + w3.x * av.w;
            oa[1][j] += w0.y * av.x + w1.y * av.y + w2.y * av.z + w3.y * av.w;
        }
    }
    float b0 = bout[ch0], b1 = bout[ch0 + 1];
    float s1 = 0.f, s2 = 0.f;
#pragma unroll
    for (int j = 0; j < 16; j++) {
        float o0 = oa[0][j] + b0, o1 = oa[1][j] + b1;
        s1 += o0 + o1;
        s2 += o0 * o0 + o1 * o1;
        *(float2*)&out[(tok0 + tg * 16 + j) * NCH + ch0] = make_float2(o0, o1);
    }
#pragma unroll
    for (int off = 32; off > 0; off >>= 1) {
        s1 += __shfl_down(s1, off);
        s2 += __shfl_down(s2, off);
    }
    if ((t & 63) == 0) {
        atomicAdd(&ws[GNS_OFF + batch * 2 + 0], s1);
        atomicAdd(&ws[GNS_OFF + batch * 2 + 1], s2);
    }
}

__global__ void k_gnfinal(float* __restrict__ ws) {
    int b = threadIdx.x;
    if (b < BATCH) {
        const float n = (float)NCH * (float)SEQL;
        float s1 = ws[GNS_OFF + b * 2], s2 = ws[GNS_OFF + b * 2 + 1];
        float mean = s1 / n;
        float var = s2 / n - mean * mean;
        ws[GNF_OFF + b * 2] = mean;
        ws[GNF_OFF + b * 2 + 1] = rsqrtf(var + GEPS);
    }
}

__global__ __launch_bounds__(256) void k_gnorm(float* __restrict__ out,
                                               const float* __restrict__ ws,
                                               const float* __restrict__ gw,
                                               const float* __restrict__ gb) {
    size_t i4 = (size_t)blockIdx.x * 256 + threadIdx.x;
    int b = (int)(i4 >> 19);                 // 2^19 float4 per batch
    int c4 = (int)(i4 & 31);
    float mean = ws[GNF_OFF + b * 2], rstd = ws[GNF_OFF + b * 2 + 1];
    float4 w = *(const float4*)&gw[c4 * 4];
    float4 bb = *(const float4*)&gb[c4 * 4];
    float4 v = ((float4*)out)[i4];
    v.x = (v.x - mean) * rstd * w.x + bb.x;
    v.y = (v.y - mean) * rstd * w.y + bb.y;
    v.z = (v.z - mean) * rstd * w.z + bb.z;
    v.w = (v.w - mean) * rstd * w.w + bb.w;
    ((float4*)out)[i4] = v;
}

extern "C" void kernel_launch(void* const* d_in, const int* in_sizes, int n_in,
                              void* d_out, int out_size, void* d_ws, size_t ws_size,
                              hipStream_t stream) {
    const float* x    = (const float*)d_in[0];
    const float* wqkv = (const float*)d_in[1];
    const float* wout = (const float*)d_in[2];
    const float* bout = (const float*)d_in[3];
    const float* gw   = (const float*)d_in[4];
    const float* gb   = (const float*)d_in[5];
    float* out = (float*)d_out;
    float* ws  = (float*)d_ws;

    hipMemsetAsync(ws + ZERO_OFF, 0, ZERO_CNT * sizeof(float), stream);
    k_prep<<<192, 256, 0, stream>>>(wqkv, wout, ws);
    k_pass1<<<512, 256, 0, stream>>>(x, ws);
    k_ctxnorm<<<128, 256, 0, stream>>>(ws);
    k_pass2<<<2048, 256, 0, stream>>>(x, bout, ws, out);
    k_gnfinal<<<1, 64, 0, stream>>>(ws);
    k_gnorm<<<16384, 256, 0, stream>>>(out, ws, gw, gb);
}

// Round 2
// 230.302 us; speedup vs baseline: 2.8184x; 2.8184x over previous
//
#include <hip/hip_runtime.h>

#define BATCH 8
#define SEQL 16384
#define NCH 128
#define NH 4
#define HD 32
#define GEPS 1e-5f

typedef __bf16 bf16x8 __attribute__((ext_vector_type(8)));
typedef __bf16 bf16x4 __attribute__((ext_vector_type(4)));
typedef float f32x4 __attribute__((ext_vector_type(4)));

// ---- workspace byte offsets ----
#define WKV_B   0          // 256*128 bf16 = 64 KiB   [o'][c], o' = o-128 (k:0..127, v:128..255)
#define WQ_B    65536      // 128*128 bf16 = 32 KiB   [o][c]
#define WO_B    98304      // 128*128 bf16 = 32 KiB   [o][c]
#define CTXB_B  131072     // 8*4*32*32 bf16 = 64 KiB [b][h][c][d]
#define CTXF_B  196608     // 8*4*32*32 f32 = 128 KiB
#define ZF_B    327680     // 8*128 f32 = 4 KiB
#define GNS_B   331776     // 8*2 f32
#define GNF_B   331840     // 8*2 f32
#define ZERO_BYTES (131072 + 4096 + 64 + 64)

// LDS strides (bf16 units)
// xb: [kblk 4][qc 4][tok 64][ki 8]; qc-stride 520, kblk-stride 2088
// ekv: [ts 2][qt 4][o 256][ti 8]; qt-stride 2056, ts-stride 8232
// pB/attB: [h|ks 4][dq 4][t 64][di 8]; dq-stride 520, h-stride 2088

__global__ void k_prep(const float* __restrict__ wqkv, const float* __restrict__ wout,
                       char* __restrict__ wsb) {
    int i = blockIdx.x * 256 + threadIdx.x;
    __bf16* wkvb = (__bf16*)(wsb + WKV_B);
    __bf16* wqb  = (__bf16*)(wsb + WQ_B);
    __bf16* wob  = (__bf16*)(wsb + WO_B);
    if (i < 384 * 128) {
        int o = i >> 7, c = i & 127;
        __bf16 v = (__bf16)wqkv[i];
        if (o < 128) wqb[o * 128 + c] = v;
        else         wkvb[(o - 128) * 128 + c] = v;
    }
    if (i < 128 * 128) wob[i] = (__bf16)wout[i];
}

// Pass 1: kv = Wkv @ x (MFMA); ek = exp(k); ctx_raw += ek (outer) v (MFMA); Z += ek
__global__ __launch_bounds__(256, 2) void k_pass1(const float* __restrict__ x,
                                                  char* __restrict__ wsb) {
    __shared__ __attribute__((aligned(16))) __bf16 xb[8352];
    __shared__ __attribute__((aligned(16))) __bf16 ekv[16464];
    const int t = threadIdx.x;
    const int lane = t & 63, wave = t >> 6;
    const int n16 = lane & 15, q = lane >> 4;
    const int batch = blockIdx.x >> 6, sub = blockIdx.x & 63;
    const __bf16* __restrict__ wkvb = (const __bf16*)(wsb + WKV_B);

    // preload Wkv A-fragments: wave covers o = wave*64 + mt*16 + n16
    bf16x8 aw[4][4];
#pragma unroll
    for (int mt = 0; mt < 4; mt++)
#pragma unroll
        for (int ks = 0; ks < 4; ks++)
            aw[mt][ks] = *(const bf16x8*)&wkvb[(wave * 64 + mt * 16 + n16) * 128 + ks * 32 + q * 8];

    f32x4 ctxacc[2][2];
#pragma unroll
    for (int i = 0; i < 2; i++)
#pragma unroll
        for (int j = 0; j < 2; j++) ctxacc[i][j] = (f32x4){0.f, 0.f, 0.f, 0.f};
    float zacc[4][4];
#pragma unroll
    for (int i = 0; i < 4; i++)
#pragma unroll
        for (int j = 0; j < 4; j++) zacc[i][j] = 0.f;

    for (int rep = 0; rep < 4; rep++) {
        const int chunk = sub + rep * 64;
        const float* xg = x + (size_t)(batch * SEQL + chunk * 64) * NCH;
        // stage x -> bf16 LDS in B-operand layout
#pragma unroll
        for (int r = 0; r < 8; r++) {
            int e = t + r * 256;
            int tok = e >> 5, c4 = (e & 31) * 4;
            float4 v = ((const float4*)xg)[e];
            bf16x4 h; h.x = (__bf16)v.x; h.y = (__bf16)v.y; h.z = (__bf16)v.z; h.w = (__bf16)v.w;
            *(bf16x4*)&xb[(c4 >> 5) * 2088 + ((c4 >> 3) & 3) * 520 + tok * 8 + (c4 & 7)] = h;
        }
        __syncthreads();
        // KV GEMM: D[o][t], o = wave*64 + mt*16 + (row), t = nt*16 + (col)
        f32x4 kvacc[4][4];
#pragma unroll
        for (int i = 0; i < 4; i++)
#pragma unroll
            for (int j = 0; j < 4; j++) kvacc[i][j] = (f32x4){0.f, 0.f, 0.f, 0.f};
#pragma unroll
        for (int ks = 0; ks < 4; ks++) {
            bf16x8 b[4];
#pragma unroll
            for (int nt = 0; nt < 4; nt++)
                b[nt] = *(const bf16x8*)&xb[ks * 2088 + q * 520 + (nt * 16 + n16) * 8];
#pragma unroll
            for (int mt = 0; mt < 4; mt++)
#pragma unroll
                for (int nt = 0; nt < 4; nt++)
                    kvacc[mt][nt] = __builtin_amdgcn_mfma_f32_16x16x32_bf16(
                        aw[mt][ks], b[nt], kvacc[mt][nt], 0, 0, 0);
        }
        // exp (k-waves), accumulate Z, write ekv LDS in frag-friendly layout
#pragma unroll
        for (int mt = 0; mt < 4; mt++)
#pragma unroll
            for (int nt = 0; nt < 4; nt++) {
                int tt = nt * 16 + n16;
                int base = (tt >> 5) * 8232 + ((tt >> 3) & 3) * 2056 + (tt & 7);
#pragma unroll
                for (int r = 0; r < 4; r++) {
                    float vv = kvacc[mt][nt][r];
                    if (wave < 2) { vv = __expf(vv); zacc[mt][r] += vv; }
                    int o = wave * 64 + mt * 16 + q * 4 + r;
                    ekv[base + o * 8] = (__bf16)vv;
                }
            }
        __syncthreads();
        // ctx MFMA: wave = head h; A = ek[c][t] (c = h*32..), B = v[d][t]
#pragma unroll
        for (int ks2 = 0; ks2 < 2; ks2++) {
            bf16x8 ea[2], vb[2];
#pragma unroll
            for (int ml = 0; ml < 2; ml++) {
                ea[ml] = *(const bf16x8*)&ekv[ks2 * 8232 + q * 2056 + (wave * 32 + ml * 16 + n16) * 8];
                vb[ml] = *(const bf16x8*)&ekv[ks2 * 8232 + q * 2056 + (128 + wave * 32 + ml * 16 + n16) * 8];
            }
#pragma unroll
            for (int ml = 0; ml < 2; ml++)
#pragma unroll
                for (int nl = 0; nl < 2; nl++)
                    ctxacc[ml][nl] = __builtin_amdgcn_mfma_f32_16x16x32_bf16(
                        ea[ml], vb[nl], ctxacc[ml][nl], 0, 0, 0);
        }
        __syncthreads();
    }
    // ctx atomics: lane holds ctx[c = ml*16+q*4+r][d = nl*16+n16] for head=wave
    float* ctxf = (float*)(wsb + CTXF_B) + ((size_t)(batch * 4 + wave) * 32) * 32;
#pragma unroll
    for (int ml = 0; ml < 2; ml++)
#pragma unroll
        for (int nl = 0; nl < 2; nl++)
#pragma unroll
            for (int r = 0; r < 4; r++)
                atomicAdd(&ctxf[(ml * 16 + q * 4 + r) * 32 + nl * 16 + n16], ctxacc[ml][nl][r]);
    // Z: sum over tokens = butterfly over n16 lanes
    if (wave < 2) {
        float* Zf = (float*)(wsb + ZF_B) + batch * 128;
#pragma unroll
        for (int mt = 0; mt < 4; mt++)
#pragma unroll
            for (int r = 0; r < 4; r++) {
                float z = zacc[mt][r];
                z += __shfl_xor(z, 1); z += __shfl_xor(z, 2);
                z += __shfl_xor(z, 4); z += __shfl_xor(z, 8);
                if (n16 == 0) atomicAdd(&Zf[wave * 64 + mt * 16 + q * 4 + r], z);
            }
    }
}

__global__ void k_ctxnorm(char* __restrict__ wsb) {
    int i = blockIdx.x * 256 + threadIdx.x;
    if (i < BATCH * NH * HD * HD) {
        const float* ctxf = (const float*)(wsb + CTXF_B);
        const float* Zf = (const float*)(wsb + ZF_B);
        __bf16* ctxb = (__bf16*)(wsb + CTXB_B);
        int c = (i >> 5) & 31, h = (i >> 10) & 3, b = i >> 12;
        ctxb[i] = (__bf16)(ctxf[i] / Zf[b * 128 + h * 32 + c]);
    }
}

// Pass 2: q = Wq @ x (MFMA); softmax over head-dim in registers; attn = ctx @ p (MFMA);
// out = Wout @ attn + bias (MFMA); GN partial sums; store pre-GN out.
__global__ __launch_bounds__(256, 2) void k_pass2(const float* __restrict__ x,
                                                  const float* __restrict__ bout,
                                                  char* __restrict__ wsb,
                                                  float* __restrict__ out) {
    __shared__ __attribute__((aligned(16))) __bf16 xb[8352];
    __shared__ __attribute__((aligned(16))) __bf16 pB[8352];
    __shared__ __attribute__((aligned(16))) __bf16 attB[8352];
    const int t = threadIdx.x;
    const int lane = t & 63, wave = t >> 6;       // wave == head h
    const int n16 = lane & 15, q = lane >> 4;
    const int batch = blockIdx.x >> 6, sub = blockIdx.x & 63;
    const __bf16* __restrict__ wqb = (const __bf16*)(wsb + WQ_B);
    const __bf16* __restrict__ wob = (const __bf16*)(wsb + WO_B);
    const __bf16* __restrict__ ctxb = (const __bf16*)(wsb + CTXB_B);

    bf16x8 aq[2][4], ao[2][4];
#pragma unroll
    for (int ml = 0; ml < 2; ml++)
#pragma unroll
        for (int ks = 0; ks < 4; ks++) {
            aq[ml][ks] = *(const bf16x8*)&wqb[(wave * 32 + ml * 16 + n16) * 128 + ks * 32 + q * 8];
            ao[ml][ks] = *(const bf16x8*)&wob[(wave * 32 + ml * 16 + n16) * 128 + ks * 32 + q * 8];
        }
    bf16x8 actx[2];
#pragma unroll
    for (int ml = 0; ml < 2; ml++)
        actx[ml] = *(const bf16x8*)&ctxb[((size_t)(batch * 4 + wave) * 32 + ml * 16 + n16) * 32 + q * 8];
    float4 bias[2];
#pragma unroll
    for (int ml = 0; ml < 2; ml++)
        bias[ml] = *(const float4*)&bout[wave * 32 + ml * 16 + q * 4];

    float s1 = 0.f, s2 = 0.f;

    for (int rep = 0; rep < 4; rep++) {
        const int chunk = sub + rep * 64;
        const size_t tok0 = (size_t)batch * SEQL + chunk * 64;
        const float* xg = x + tok0 * NCH;
#pragma unroll
        for (int r = 0; r < 8; r++) {
            int e = t + r * 256;
            int tok = e >> 5, c4 = (e & 31) * 4;
            float4 v = ((const float4*)xg)[e];
            bf16x4 h; h.x = (__bf16)v.x; h.y = (__bf16)v.y; h.z = (__bf16)v.z; h.w = (__bf16)v.w;
            *(bf16x4*)&xb[(c4 >> 5) * 2088 + ((c4 >> 3) & 3) * 520 + tok * 8 + (c4 & 7)] = h;
        }
        __syncthreads();
        // Wq GEMM: wave handles head's 32 q-channels (mtiles 2h, 2h+1)
        f32x4 qacc[2][4];
#pragma unroll
        for (int i = 0; i < 2; i++)
#pragma unroll
            for (int j = 0; j < 4; j++) qacc[i][j] = (f32x4){0.f, 0.f, 0.f, 0.f};
#pragma unroll
        for (int ks = 0; ks < 4; ks++) {
            bf16x8 b[4];
#pragma unroll
            for (int nt = 0; nt < 4; nt++)
                b[nt] = *(const bf16x8*)&xb[ks * 2088 + q * 520 + (nt * 16 + n16) * 8];
#pragma unroll
            for (int ml = 0; ml < 2; ml++)
#pragma unroll
                for (int nt = 0; nt < 4; nt++)
                    qacc[ml][nt] = __builtin_amdgcn_mfma_f32_16x16x32_bf16(
                        aq[ml][ks], b[nt], qacc[ml][nt], 0, 0, 0);
        }
        // softmax over the 32 head channels, entirely in registers + 2 shuffles
#pragma unroll
        for (int nt = 0; nt < 4; nt++) {
            float ss = 0.f;
#pragma unroll
            for (int ml = 0; ml < 2; ml++)
#pragma unroll
                for (int r = 0; r < 4; r++) {
                    float e = __expf(qacc[ml][nt][r]);
                    qacc[ml][nt][r] = e;
                    ss += e;
                }
            ss += __shfl_xor(ss, 16);
            ss += __shfl_xor(ss, 32);
            float inv = 0.17677669529663687f / ss;   // (1/sqrt(32)) / denom
#pragma unroll
            for (int ml = 0; ml < 2; ml++)
#pragma unroll
                for (int r = 0; r < 4; r++) qacc[ml][nt][r] *= inv;
        }
        // write p to LDS: p[d = ml*16+q*4+r][t], layout [h][d>>3][t][d&7]
#pragma unroll
        for (int ml = 0; ml < 2; ml++)
#pragma unroll
            for (int nt = 0; nt < 4; nt++) {
                bf16x4 h;
                h.x = (__bf16)qacc[ml][nt][0]; h.y = (__bf16)qacc[ml][nt][1];
                h.z = (__bf16)qacc[ml][nt][2]; h.w = (__bf16)qacc[ml][nt][3];
                *(bf16x4*)&pB[wave * 2088 + (ml * 2 + (q >> 1)) * 520 +
                              (nt * 16 + n16) * 8 + (q & 1) * 4] = h;
            }
        __syncthreads();
        // attn MFMA: A = ctx[h] (32c x 32d), B = p[h] (32d x 64t)
        f32x4 aacc[2][4];
#pragma unroll
        for (int ml = 0; ml < 2; ml++)
#pragma unroll
            for (int nt = 0; nt < 4; nt++) {
                bf16x8 pb = *(const bf16x8*)&pB[wave * 2088 + q * 520 + (nt * 16 + n16) * 8];
                aacc[ml][nt] = __builtin_amdgcn_mfma_f32_16x16x32_bf16(
                    actx[ml], pb, (f32x4){0.f, 0.f, 0.f, 0.f}, 0, 0, 0);
            }
        // write attn to LDS: c_in = h*32 + ml*16 + q*4 + r, layout [c>>5][ (c>>3)&3 ][t][c&7]
#pragma unroll
        for (int ml = 0; ml < 2; ml++)
#pragma unroll
            for (int nt = 0; nt < 4; nt++) {
                bf16x4 h;
                h.x = (__bf16)aacc[ml][nt][0]; h.y = (__bf16)aacc[ml][nt][1];
                h.z = (__bf16)aacc[ml][nt][2]; h.w = (__bf16)aacc[ml][nt][3];
                *(bf16x4*)&attB[wave * 2088 + (ml * 2 + (q >> 1)) * 520 +
                                (nt * 16 + n16) * 8 + (q & 1) * 4] = h;
            }
        __syncthreads();
        // Wout GEMM: wave covers out channels o = wave*32 + ml*16 + ...
        f32x4 oacc[2][4];
#pragma unroll
        for (int i = 0; i < 2; i++)
#pragma unroll
            for (int j = 0; j < 4; j++) oacc[i][j] = (f32x4){0.f, 0.f, 0.f, 0.f};
#pragma unroll
        for (int ks = 0; ks < 4; ks++) {
            bf16x8 b[4];
#pragma unroll
            for (int nt = 0; nt < 4; nt++)
                b[nt] = *(const bf16x8*)&attB[ks * 2088 + q * 520 + (nt * 16 + n16) * 8];
#pragma unroll
            for (int ml = 0; ml < 2; ml++)
#pragma unroll
                for (int nt = 0; nt < 4; nt++)
                    oacc[ml][nt] = __builtin_amdgcn_mfma_f32_16x16x32_bf16(
                        ao[ml][ks], b[nt], oacc[ml][nt], 0, 0, 0);
        }
        // epilogue: bias, GN sums, store
#pragma unroll
        for (int ml = 0; ml < 2; ml++)
#pragma unroll
            for (int nt = 0; nt < 4; nt++) {
                float4 vv;
                vv.x = oacc[ml][nt][0] + bias[ml].x;
                vv.y = oacc[ml][nt][1] + bias[ml].y;
                vv.z = oacc[ml][nt][2] + bias[ml].z;
                vv.w = oacc[ml][nt][3] + bias[ml].w;
                s1 += vv.x + vv.y + vv.z + vv.w;
                s2 += vv.x * vv.x + vv.y * vv.y + vv.z * vv.z + vv.w * vv.w;
                *(float4*)&out[(tok0 + nt * 16 + n16) * NCH + wave * 32 + ml * 16 + q * 4] = vv;
            }
        __syncthreads();
    }
#pragma unroll
    for (int off = 32; off > 0; off >>= 1) {
        s1 += __shfl_xor(s1, off);
        s2 += __shfl_xor(s2, off);
    }
    if (lane == 0) {
        float* gns = (float*)(wsb + GNS_B);
        atomicAdd(&gns[batch * 2 + 0], s1);
        atomicAdd(&gns[batch * 2 + 1], s2);
    }
}

__global__ void k_gnfinal(char* __restrict__ wsb) {
    int b = threadIdx.x;
    if (b < BATCH) {
        const float n = (float)NCH * (float)SEQL;
        const float* gns = (const float*)(wsb + GNS_B);
        float* gnf = (float*)(wsb + GNF_B);
        float mean = gns[b * 2] / n;
        float var = gns[b * 2 + 1] / n - mean * mean;
        gnf[b * 2] = mean;
        gnf[b * 2 + 1] = rsqrtf(var + GEPS);
    }
}

__global__ __launch_bounds__(256) void k_gnorm(float* __restrict__ out,
                                               const char* __restrict__ wsb,
                                               const float* __restrict__ gw,
                                               const float* __restrict__ gb) {
    size_t i4 = (size_t)blockIdx.x * 256 + threadIdx.x;
    int b = (int)(i4 >> 19);
    int c4 = (int)(i4 & 31);
    const float* gnf = (const float*)(wsb + GNF_B);
    float mean = gnf[b * 2], rstd = gnf[b * 2 + 1];
    float4 w = *(const float4*)&gw[c4 * 4];
    float4 bb = *(const float4*)&gb[c4 * 4];
    float4 v = ((float4*)out)[i4];
    v.x = (v.x - mean) * rstd * w.x + bb.x;
    v.y = (v.y - mean) * rstd * w.y + bb.y;
    v.z = (v.z - mean) * rstd * w.z + bb.z;
    v.w = (v.w - mean) * rstd * w.w + bb.w;
    ((float4*)out)[i4] = v;
}

extern "C" void kernel_launch(void* const* d_in, const int* in_sizes, int n_in,
                              void* d_out, int out_size, void* d_ws, size_t ws_size,
                              hipStream_t stream) {
    const float* x    = (const float*)d_in[0];
    const float* wqkv = (const float*)d_in[1];
    const float* wout = (const float*)d_in[2];
    const float* bout = (const float*)d_in[3];
    const float* gw   = (const float*)d_in[4];
    const float* gb   = (const float*)d_in[5];
    float* out = (float*)d_out;
    char* wsb  = (char*)d_ws;

    hipMemsetAsync(wsb + CTXF_B, 0, ZERO_BYTES, stream);
    k_prep<<<192, 256, 0, stream>>>(wqkv, wout, wsb);
    k_pass1<<<512, 256, 0, stream>>>(x, wsb);
    k_ctxnorm<<<128, 256, 0, stream>>>(wsb);
    k_pass2<<<512, 256, 0, stream>>>(x, bout, wsb, out);
    k_gnfinal<<<1, 64, 0, stream>>>(wsb);
    k_gnorm<<<16384, 256, 0, stream>>>(out, wsb, gw, gb);
}